// Round 7
// baseline (274.753 us; speedup 1.0000x reference)
//
#include <hip/hip_runtime.h>
#include <hip/hip_bf16.h>

typedef _Float16 half2v __attribute__((ext_vector_type(2)));
typedef _Float16 half8  __attribute__((ext_vector_type(8)));
typedef __fp16   fp16x2 __attribute__((ext_vector_type(2)));
typedef float f32x4 __attribute__((ext_vector_type(4)));

union FragF16 { half8 v; half2v h[4]; };
union Cvt2 { fp16x2 f; half2v h; };

// Block = 2 waves (128 thr) over 16 b's: wave = d (0/1). Grid = 2048.
// Per wave-iteration: 16 grid points (n = c*16 + lrow) of one b through the
// 64x64 layer via 8 f16 MFMAs. Layer-1 + leaky in packed fp16 (result is
// directly the MFMA B-operand). Epilogue: p1 = 0.505*w3^T(W2 h1 + b2) via
// v_dot2 on h1 pairs; p2 = 0.495*w3.|h2| via cvt_pkrtz(|dacc|) + v_dot2.
// Registers trimmed (no SW pipeline, fp16 w3) to raise waves/SIMD —
// R6 analysis: kernel is latency-bound at ~2 waves/SIMD, ~25% issue util.
//
// NOTE: no 2nd __launch_bounds__ arg — (256,4) forced a 64-VGPR budget and
// spilled all persistent fragments to scratch (1.9 GB FETCH, 657 us; R5).
__global__ __launch_bounds__(128) void monotone_nn_kernel(
    const float* __restrict__ zin, const float* __restrict__ uin,
    const float* __restrict__ w01, const float* __restrict__ b01,
    const float* __restrict__ w02, const float* __restrict__ b02,
    const float* __restrict__ w03, const float* __restrict__ b03,
    const float* __restrict__ w11, const float* __restrict__ b11,
    const float* __restrict__ w12, const float* __restrict__ b12,
    const float* __restrict__ w13, const float* __restrict__ b13,
    const float* __restrict__ biasp, const int* __restrict__ lbp,
    float* __restrict__ out)
{
    __shared__ float lds_hz[2][16];
    __shared__ float lds_v[2][64];

    const int tid  = threadIdx.x;
    const int lane = tid & 63;
    const int d    = tid >> 6;     // wave index = MLP selector
    const int lrow = lane & 15;    // MFMA col index (grid point) / A-row within tile
    const int quad = lane >> 4;

    const int b0 = blockIdx.x * 16;   // 16 b's per block (both waves share them)

    const float lb    = (float)lbp[0];
    const float biasv = biasp[0];

    const float* w1p = d ? w11 : w01;
    const float* b1p = d ? b11 : b01;
    const float* w2p = d ? w12 : w02;
    const float* b2p = d ? b12 : b02;
    const float* w3p = d ? w13 : w03;
    const float  b3  = (d ? b13 : b03)[0];

    // --- vfold = 0.505 * (w3^T W2): one column per lane, coalesced ---
    {
        float va = 0.0f;
        #pragma unroll 8
        for (int f = 0; f < 64; ++f)
            va = fmaf(w3p[f], w2p[f * 64 + lane], va);
        lds_v[d][lane] = 0.505f * va;
    }

    // --- preload per-lane weight slices ---
    // layer-1 packed fp16: lane computes h1[h] for h = kc*32 + quad*8 + j
    half2v w1pk[8], b1pk[8];
    #pragma unroll
    for (int kc = 0; kc < 2; ++kc)
        #pragma unroll
        for (int jj = 0; jj < 4; ++jj) {
            const int h = kc * 32 + quad * 8 + 2 * jj;
            half2v w, bb;
            w[0]  = (_Float16)w1p[h];     w[1]  = (_Float16)w1p[h + 1];
            bb[0] = (_Float16)b1p[h];     bb[1] = (_Float16)b1p[h + 1];
            w1pk[kc * 4 + jj] = w;
            b1pk[kc * 4 + jj] = bb;
        }

    // epilogue: lane holds h2 features f = t*16 + quad*4 + r
    // w3 (x0.495 folded) as fp16 pairs; b2 as f32 C-operand init
    half2v w3pk[8];
    f32x4 b2v[4];
    float bd = 0.0f;
    #pragma unroll
    for (int t = 0; t < 4; ++t) {
        #pragma unroll
        for (int r = 0; r < 4; ++r) {
            const int f = t * 16 + quad * 4 + r;
            b2v[t][r] = b2p[f];
            bd = fmaf(w3p[f], b2p[f], bd);
        }
        #pragma unroll
        for (int rr = 0; rr < 2; ++rr) {
            const int f = t * 16 + quad * 4 + 2 * rr;
            half2v w;
            w[0] = (_Float16)(0.495f * w3p[f]);
            w[1] = (_Float16)(0.495f * w3p[f + 1]);
            w3pk[t * 2 + rr] = w;
        }
    }
    // b3' = b3 + 0.505*(w3.b2)
    bd += __shfl_xor(bd, 16);
    bd += __shfl_xor(bd, 32);
    const float b3p_ = b3 + 0.505f * bd;

    // A-frags (fp16): A[f][h] = w2[f][h]; frag (t,kc): w2[t*16+lrow][kc*32+quad*8+j]
    FragF16 afrag[8];
    #pragma unroll
    for (int t = 0; t < 4; ++t)
        #pragma unroll
        for (int kc = 0; kc < 2; ++kc) {
            const float* src = w2p + (t * 16 + lrow) * 64 + kc * 32 + quad * 8;
            #pragma unroll
            for (int j = 0; j < 8; ++j)
                afrag[t * 2 + kc].v[j] = (_Float16)src[j];
        }

    __syncthreads();

    // vfold pairs as fp16, matching bfrag pair layout (k = kc*32+quad*8+2jj)
    half2v vpk[8];
    #pragma unroll
    for (int kc = 0; kc < 2; ++kc)
        #pragma unroll
        for (int jj = 0; jj < 4; ++jj) {
            const float2 vv = *(const float2*)&lds_v[d][kc * 32 + quad * 8 + 2 * jj];
            half2v t;
            t[0] = (_Float16)vv.x;
            t[1] = (_Float16)vv.y;
            vpk[kc * 4 + jj] = t;
        }

    const float lrowf = (float)lrow;
    const half2v k001 = { (_Float16)0.01f, (_Float16)0.01f };

    #pragma unroll 2
    for (int i = 0; i < 16; ++i) {
        const int b = b0 + i;
        const float zv = zin[b * 2 + d];
        const float ds = (fmaxf(zv, lb) - lb) * (1.0f / 127.0f);
        const float* ub = uin + (size_t)(b * 2 + d) * 127;
        float acc = 0.0f;

        #pragma unroll
        for (int c = 0; c < 8; ++c) {
            const int n = c * 16 + lrow;
            float uv;
            if (c < 7) uv = ub[n];
            else       uv = (lrow < 15) ? ub[n] : 0.0f;   // last grid point: no jitter
            const float x = fmaf(ds, lrowf + (float)(c * 16) + uv, lb);

            // broadcast x into a packed fp16 pair
            const _Float16 xh = (_Float16)x;
            const half2v x2 = { xh, xh };

            // B-frag: h1 = pk_max(t, 0.01*t), t = pk_fma(x2, w1, b1)
            FragF16 bfrag[2];
            #pragma unroll
            for (int kc = 0; kc < 2; ++kc)
                #pragma unroll
                for (int jj = 0; jj < 4; ++jj) {
                    const half2v t0 = x2 * w1pk[kc * 4 + jj] + b1pk[kc * 4 + jj];
                    bfrag[kc].h[jj] = __builtin_elementwise_max(t0, t0 * k001);
                }

            // p1 = vfold . h1 directly from the fp16 pairs (v_dot2_f32_f16)
            float p1 = 0.0f;
            #pragma unroll
            for (int kc = 0; kc < 2; ++kc)
                #pragma unroll
                for (int jj = 0; jj < 4; ++jj)
                    p1 = __builtin_amdgcn_fdot2(bfrag[kc].h[jj], vpk[kc * 4 + jj], p1, false);

            // p2 = (0.495*w3) . |h2|: pack |dacc| pairs -> dot2
            float p2 = 0.0f;
            #pragma unroll
            for (int t = 0; t < 4; ++t) {
                f32x4 dacc;
                dacc = __builtin_amdgcn_mfma_f32_16x16x32_f16(afrag[t * 2 + 0].v, bfrag[0].v, b2v[t], 0, 0, 0);
                dacc = __builtin_amdgcn_mfma_f32_16x16x32_f16(afrag[t * 2 + 1].v, bfrag[1].v, dacc,   0, 0, 0);
                #pragma unroll
                for (int rr = 0; rr < 2; ++rr) {
                    Cvt2 cv;
                    cv.f = __builtin_amdgcn_cvt_pkrtz(fabsf(dacc[2 * rr]), fabsf(dacc[2 * rr + 1]));
                    p2 = __builtin_amdgcn_fdot2(cv.h, w3pk[t * 2 + rr], p2, false);
                }
            }
            float p = p1 + p2;
            p += __shfl_xor(p, 16);
            p += __shfl_xor(p, 32);
            const float s = p + b3p_;
            // elu(s)+1 = s>0 ? s+1 : exp(s)
            const float e = __builtin_amdgcn_exp2f(s * 1.4426950408889634f);
            acc += (s > 0.0f) ? (s + 1.0f) : e;
        }

        // reduce the 16 per-n accumulators (quads already replicated by the shuffles)
        acc += __shfl_xor(acc, 1);
        acc += __shfl_xor(acc, 2);
        acc += __shfl_xor(acc, 4);
        acc += __shfl_xor(acc, 8);

        if (lane == 0) lds_hz[d][i] = acc * ds;
    }

    __syncthreads();
    if (tid < 16)
        out[b0 + tid] = lds_hz[0][tid] + lds_hz[1][tid] + biasv;
}

extern "C" void kernel_launch(void* const* d_in, const int* in_sizes, int n_in,
                              void* d_out, int out_size, void* d_ws, size_t ws_size,
                              hipStream_t stream) {
    const float* z    = (const float*)d_in[0];
    const float* u    = (const float*)d_in[1];
    const float* w0_1 = (const float*)d_in[2];
    const float* b0_1 = (const float*)d_in[3];
    const float* w0_2 = (const float*)d_in[4];
    const float* b0_2 = (const float*)d_in[5];
    const float* w0_3 = (const float*)d_in[6];
    const float* b0_3 = (const float*)d_in[7];
    const float* w1_1 = (const float*)d_in[8];
    const float* b1_1 = (const float*)d_in[9];
    const float* w1_2 = (const float*)d_in[10];
    const float* b1_2 = (const float*)d_in[11];
    const float* w1_3 = (const float*)d_in[12];
    const float* b1_3 = (const float*)d_in[13];
    const float* bias = (const float*)d_in[14];
    const int*   lbp  = (const int*)d_in[16];

    // 32768 b: each block covers 16 b's with 2 waves (d=0, d=1)
    monotone_nn_kernel<<<dim3(2048), dim3(128), 0, stream>>>(
        z, u, w0_1, b0_1, w0_2, b0_2, w0_3, b0_3,
        w1_1, b1_1, w1_2, b1_2, w1_3, b1_3,
        bias, lbp, (float*)d_out);
}

// Round 8
// 215.648 us; speedup vs baseline: 1.2741x; 1.2741x over previous
//
#include <hip/hip_runtime.h>
#include <hip/hip_bf16.h>

typedef _Float16 half2v __attribute__((ext_vector_type(2)));
typedef _Float16 half8  __attribute__((ext_vector_type(8)));
typedef __fp16   fp16x2 __attribute__((ext_vector_type(2)));
typedef float f32x4 __attribute__((ext_vector_type(4)));

union FragF16 { half8 v; half2v h[4]; };
union Cvt2 { fp16x2 f; half2v h; };

// Block = 4 waves over 32 b's: wave w -> d = w&1, b-group = w>>1 (16 b's each).
// Latency-bound kernel (R6/R7 analysis): the per-c-iter chain
// (x -> h1 -> MFMA x2 -> dots -> 2x ds_swizzle -> exp) ~250 cyc vs ~130 cyc
// issue; occupancy pinned at ~4 waves/SIMD. So: explicit 2-way ILP — two b's
// (even/odd) interleaved through the whole inner loop, independent chains.
// z/u prefetched one PAIR ahead (R7 showed removing prefetch costs ~60 us).
//
// NOTE: no 2nd __launch_bounds__ arg — (256,4) forced a 64-VGPR budget and
// spilled all persistent fragments to scratch (1.9 GB FETCH, 657 us; R5).
__global__ __launch_bounds__(256) void monotone_nn_kernel(
    const float* __restrict__ zin, const float* __restrict__ uin,
    const float* __restrict__ w01, const float* __restrict__ b01,
    const float* __restrict__ w02, const float* __restrict__ b02,
    const float* __restrict__ w03, const float* __restrict__ b03,
    const float* __restrict__ w11, const float* __restrict__ b11,
    const float* __restrict__ w12, const float* __restrict__ b12,
    const float* __restrict__ w13, const float* __restrict__ b13,
    const float* __restrict__ biasp, const int* __restrict__ lbp,
    float* __restrict__ out)
{
    __shared__ float lds_hz[4][16];
    __shared__ float lds_v[2][64];

    const int tid  = threadIdx.x;
    const int lane = tid & 63;
    const int wave = tid >> 6;
    const int lrow = lane & 15;   // MFMA col index (grid point) / A-row within tile
    const int quad = lane >> 4;

    const int d  = wave & 1;
    const int bg = wave >> 1;
    const int b0 = blockIdx.x * 32 + bg * 16;   // 16 b's per wave (8 pairs)

    const float lb    = (float)lbp[0];
    const float biasv = biasp[0];

    const float* w1p = d ? w11 : w01;
    const float* b1p = d ? b11 : b01;
    const float* w2p = d ? w12 : w02;
    const float* b2p = d ? b12 : b02;
    const float* w3p = d ? w13 : w03;
    const float  b3  = (d ? b13 : b03)[0];

    // --- cooperative vfold = 0.505 * (w3^T W2): one column per lane, coalesced ---
    if (bg == 0) {
        float va = 0.0f;
        #pragma unroll 8
        for (int f = 0; f < 64; ++f)
            va = fmaf(w3p[f], w2p[f * 64 + lane], va);
        lds_v[d][lane] = 0.505f * va;
    }

    // --- preload per-lane weight slices ---
    // layer-1 packed fp16: lane computes h1[h] for h = kc*32 + quad*8 + j
    half2v w1pk[8], b1pk[8];
    #pragma unroll
    for (int kc = 0; kc < 2; ++kc)
        #pragma unroll
        for (int jj = 0; jj < 4; ++jj) {
            const int h = kc * 32 + quad * 8 + 2 * jj;
            half2v w, bb;
            w[0]  = (_Float16)w1p[h];     w[1]  = (_Float16)w1p[h + 1];
            bb[0] = (_Float16)b1p[h];     bb[1] = (_Float16)b1p[h + 1];
            w1pk[kc * 4 + jj] = w;
            b1pk[kc * 4 + jj] = bb;
        }

    // epilogue: lane holds h2 features f = t*16 + quad*4 + r
    // w3 (x0.495) as fp16 pairs; b2 as f32 C-operand init (0 per-iter insts)
    half2v w3pk[8];
    f32x4 b2v[4];
    float bd = 0.0f;
    #pragma unroll
    for (int t = 0; t < 4; ++t) {
        #pragma unroll
        for (int r = 0; r < 4; ++r) {
            const int f = t * 16 + quad * 4 + r;
            b2v[t][r] = b2p[f];
            bd = fmaf(w3p[f], b2p[f], bd);
        }
        #pragma unroll
        for (int rr = 0; rr < 2; ++rr) {
            const int f = t * 16 + quad * 4 + 2 * rr;
            half2v w;
            w[0] = (_Float16)(0.495f * w3p[f]);
            w[1] = (_Float16)(0.495f * w3p[f + 1]);
            w3pk[t * 2 + rr] = w;
        }
    }
    // b3' = b3 + 0.505*(w3.b2)
    bd += __shfl_xor(bd, 16);
    bd += __shfl_xor(bd, 32);
    const float b3p_ = b3 + 0.505f * bd;

    // A-frags (fp16): A[f][h] = w2[f][h]; frag (t,kc): w2[t*16+lrow][kc*32+quad*8+j]
    FragF16 afrag[8];
    #pragma unroll
    for (int t = 0; t < 4; ++t)
        #pragma unroll
        for (int kc = 0; kc < 2; ++kc) {
            const float* src = w2p + (t * 16 + lrow) * 64 + kc * 32 + quad * 8;
            #pragma unroll
            for (int j = 0; j < 8; ++j)
                afrag[t * 2 + kc].v[j] = (_Float16)src[j];
        }

    __syncthreads();

    // vfold pairs as fp16, matching bfrag pair layout (k = kc*32+quad*8+2jj)
    half2v vpk[8];
    #pragma unroll
    for (int kc = 0; kc < 2; ++kc)
        #pragma unroll
        for (int jj = 0; jj < 4; ++jj) {
            const float2 vv = *(const float2*)&lds_v[d][kc * 32 + quad * 8 + 2 * jj];
            half2v t;
            t[0] = (_Float16)vv.x;
            t[1] = (_Float16)vv.y;
            vpk[kc * 4 + jj] = t;
        }

    const float lrowf = (float)lrow;
    const half2v k001 = { (_Float16)0.01f, (_Float16)0.01f };

    // --- prefetch pair 0 (z and u for both b's) ---
    float zv_n0 = zin[(b0 + 0) * 2 + d];
    float zv_n1 = zin[(b0 + 1) * 2 + d];
    float u_n0[8], u_n1[8];
    {
        const float* ub0 = uin + (size_t)((b0 + 0) * 2 + d) * 127;
        const float* ub1 = uin + (size_t)((b0 + 1) * 2 + d) * 127;
        #pragma unroll
        for (int c = 0; c < 8; ++c) {
            const int idx = c * 16 + lrow;
            const bool ok = (c < 7) || (lrow < 15);
            u_n0[c] = ok ? ub0[idx] : 0.0f;
            u_n1[c] = ok ? ub1[idx] : 0.0f;
        }
    }

    #pragma unroll 1
    for (int ip = 0; ip < 8; ++ip) {
        const float zv0 = zv_n0, zv1 = zv_n1;
        float uu0[8], uu1[8];
        #pragma unroll
        for (int c = 0; c < 8; ++c) { uu0[c] = u_n0[c]; uu1[c] = u_n1[c]; }

        // prefetch next pair
        const int ipn = (ip < 7) ? ip + 1 : 7;
        const int bn0 = b0 + 2 * ipn, bn1 = bn0 + 1;
        zv_n0 = zin[bn0 * 2 + d];
        zv_n1 = zin[bn1 * 2 + d];
        {
            const float* ub0 = uin + (size_t)(bn0 * 2 + d) * 127;
            const float* ub1 = uin + (size_t)(bn1 * 2 + d) * 127;
            #pragma unroll
            for (int c = 0; c < 8; ++c) {
                const int idx = c * 16 + lrow;
                const bool ok = (c < 7) || (lrow < 15);
                u_n0[c] = ok ? ub0[idx] : 0.0f;
                u_n1[c] = ok ? ub1[idx] : 0.0f;
            }
        }

        const float ds0 = (fmaxf(zv0, lb) - lb) * (1.0f / 127.0f);
        const float ds1 = (fmaxf(zv1, lb) - lb) * (1.0f / 127.0f);
        float acc0 = 0.0f, acc1 = 0.0f;

        #pragma unroll
        for (int c = 0; c < 8; ++c) {
            const float base = lrowf + (float)(c * 16);
            const float x0 = fmaf(ds0, base + uu0[c], lb);
            const float x1 = fmaf(ds1, base + uu1[c], lb);

            const _Float16 xh0 = (_Float16)x0, xh1 = (_Float16)x1;
            const half2v x20 = { xh0, xh0 }, x21 = { xh1, xh1 };

            // B-frags for both streams: h1 = pk_max(t, 0.01*t)
            FragF16 bf0[2], bf1[2];
            #pragma unroll
            for (int kc = 0; kc < 2; ++kc)
                #pragma unroll
                for (int jj = 0; jj < 4; ++jj) {
                    const half2v t0 = x20 * w1pk[kc * 4 + jj] + b1pk[kc * 4 + jj];
                    const half2v t1 = x21 * w1pk[kc * 4 + jj] + b1pk[kc * 4 + jj];
                    bf0[kc].h[jj] = __builtin_elementwise_max(t0, t0 * k001);
                    bf1[kc].h[jj] = __builtin_elementwise_max(t1, t1 * k001);
                }

            // p1 = vfold . h1 (v_dot2_f32_f16), independent chains
            float p10 = 0.0f, p11 = 0.0f;
            #pragma unroll
            for (int kc = 0; kc < 2; ++kc)
                #pragma unroll
                for (int jj = 0; jj < 4; ++jj) {
                    p10 = __builtin_amdgcn_fdot2(bf0[kc].h[jj], vpk[kc * 4 + jj], p10, false);
                    p11 = __builtin_amdgcn_fdot2(bf1[kc].h[jj], vpk[kc * 4 + jj], p11, false);
                }

            // p2 = (0.495*w3) . |h2| per stream
            float p20 = 0.0f, p21 = 0.0f;
            #pragma unroll
            for (int t = 0; t < 4; ++t) {
                f32x4 da0, da1;
                da0 = __builtin_amdgcn_mfma_f32_16x16x32_f16(afrag[t * 2 + 0].v, bf0[0].v, b2v[t], 0, 0, 0);
                da1 = __builtin_amdgcn_mfma_f32_16x16x32_f16(afrag[t * 2 + 0].v, bf1[0].v, b2v[t], 0, 0, 0);
                da0 = __builtin_amdgcn_mfma_f32_16x16x32_f16(afrag[t * 2 + 1].v, bf0[1].v, da0, 0, 0, 0);
                da1 = __builtin_amdgcn_mfma_f32_16x16x32_f16(afrag[t * 2 + 1].v, bf1[1].v, da1, 0, 0, 0);
                #pragma unroll
                for (int rr = 0; rr < 2; ++rr) {
                    Cvt2 c0, c1;
                    c0.f = __builtin_amdgcn_cvt_pkrtz(fabsf(da0[2 * rr]), fabsf(da0[2 * rr + 1]));
                    c1.f = __builtin_amdgcn_cvt_pkrtz(fabsf(da1[2 * rr]), fabsf(da1[2 * rr + 1]));
                    p20 = __builtin_amdgcn_fdot2(c0.h, w3pk[t * 2 + rr], p20, false);
                    p21 = __builtin_amdgcn_fdot2(c1.h, w3pk[t * 2 + rr], p21, false);
                }
            }

            float p0 = p10 + p20;
            float p1 = p11 + p21;
            p0 += __shfl_xor(p0, 16);
            p1 += __shfl_xor(p1, 16);
            p0 += __shfl_xor(p0, 32);
            p1 += __shfl_xor(p1, 32);
            const float s0 = p0 + b3p_;
            const float s1 = p1 + b3p_;
            const float e0 = __builtin_amdgcn_exp2f(s0 * 1.4426950408889634f);
            const float e1 = __builtin_amdgcn_exp2f(s1 * 1.4426950408889634f);
            acc0 += (s0 > 0.0f) ? (s0 + 1.0f) : e0;
            acc1 += (s1 > 0.0f) ? (s1 + 1.0f) : e1;
        }

        // reduce the 16 per-n accumulators (quads already replicated)
        acc0 += __shfl_xor(acc0, 1);
        acc1 += __shfl_xor(acc1, 1);
        acc0 += __shfl_xor(acc0, 2);
        acc1 += __shfl_xor(acc1, 2);
        acc0 += __shfl_xor(acc0, 4);
        acc1 += __shfl_xor(acc1, 4);
        acc0 += __shfl_xor(acc0, 8);
        acc1 += __shfl_xor(acc1, 8);

        if (lane == 0) {
            lds_hz[wave][2 * ip]     = acc0 * ds0;
            lds_hz[wave][2 * ip + 1] = acc1 * ds1;
        }
    }

    __syncthreads();
    if (tid < 32) {
        const int g = tid >> 4, l = tid & 15;
        out[blockIdx.x * 32 + g * 16 + l] = lds_hz[2 * g][l] + lds_hz[2 * g + 1][l] + biasv;
    }
}

extern "C" void kernel_launch(void* const* d_in, const int* in_sizes, int n_in,
                              void* d_out, int out_size, void* d_ws, size_t ws_size,
                              hipStream_t stream) {
    const float* z    = (const float*)d_in[0];
    const float* u    = (const float*)d_in[1];
    const float* w0_1 = (const float*)d_in[2];
    const float* b0_1 = (const float*)d_in[3];
    const float* w0_2 = (const float*)d_in[4];
    const float* b0_2 = (const float*)d_in[5];
    const float* w0_3 = (const float*)d_in[6];
    const float* b0_3 = (const float*)d_in[7];
    const float* w1_1 = (const float*)d_in[8];
    const float* b1_1 = (const float*)d_in[9];
    const float* w1_2 = (const float*)d_in[10];
    const float* b1_2 = (const float*)d_in[11];
    const float* w1_3 = (const float*)d_in[12];
    const float* b1_3 = (const float*)d_in[13];
    const float* bias = (const float*)d_in[14];
    const int*   lbp  = (const int*)d_in[16];

    // 32768 b * 2 d; each block covers 32 b's (4 waves: 2 b-groups x 2 d)
    monotone_nn_kernel<<<dim3(1024), dim3(256), 0, stream>>>(
        z, u, w0_1, b0_1, w0_2, b0_2, w0_3, b0_3,
        w1_1, b1_1, w1_2, b1_2, w1_3, b1_3,
        bias, lbp, (float*)d_out);
}